// Round 7
// baseline (68.959 us; speedup 1.0000x reference)
//
#include <hip/hip_runtime.h>
#include <hip/hip_fp16.h>

#define NOUT 50000
#define KNB 32            // neighbors per output point
#define CIN 16
#define COUT 32
#define NTAP 64
#define GP 8              // points per block (2 per wave, 4 waves)
#define ROW2B 2064        // bytes per point row in s_bl: 64*16*2 (f16) + 16 pad

typedef __attribute__((ext_vector_type(8))) _Float16 half8;
typedef __attribute__((ext_vector_type(2))) _Float16 h2v;
typedef __attribute__((ext_vector_type(4))) float f32x4;

__device__ __forceinline__ h2v pmax(h2v a, h2v b) {
  h2v d;
  asm("v_pk_max_f16 %0, %1, %2" : "=v"(d) : "v"(a), "v"(b));
  return d;
}
__device__ __forceinline__ unsigned int pkh(float lo, float hi) {
  // two f32 -> packed f16x2 (RNE), lo -> bits[15:0]
  union { __half2 h; unsigned int u; } cv;
  cv.h = __floats2half2_rn(lo, hi);
  return cv.u;
}
__device__ __forceinline__ unsigned short f2hbits(float f) {
  union { __half h; unsigned short s; } c; c.h = __float2half_rn(f); return c.s;
}

// Wf[s][g][n][j] = f16(W[kc = s*32 + g*8 + j][n]) : GEMM2 B-frag order
__global__ void prep_w_kernel(const float* __restrict__ kern,
                              unsigned short* __restrict__ wf) {
  int idx = blockIdx.x * 256 + threadIdx.x;
  if (idx >= NTAP * CIN * COUT) return;  // 32768
  int j = idx & 7;
  int n = (idx >> 3) & 31;
  int g = (idx >> 8) & 3;
  int s = idx >> 10;
  int kc = s * 32 + g * 8 + j;
  wf[idx] = f2hbits(kern[kc * COUT + n]);
}

__launch_bounds__(256, 8)
__global__ void cconv_kernel(const float* __restrict__ feats,
                             const float* __restrict__ inp_points,
                             const float* __restrict__ out_points,
                             const float* __restrict__ out_extents,
                             const float* __restrict__ scale_compat,
                             const int* __restrict__ nidx,
                             const float* __restrict__ ndist,
                             const unsigned short* __restrict__ wf,
                             const float* __restrict__ bias,
                             float* __restrict__ out) {
  // f16 B matrix; element (t,c) of point p at byte p*ROW2B + t*32 + c*2
  __shared__ __align__(16) char s_bl[GP * ROW2B];              // 16512 B
  __shared__ __align__(4) unsigned short s_tx[GP * KNB];       // 512 B each
  __shared__ __align__(4) unsigned short s_ty[GP * KNB];
  __shared__ __align__(4) unsigned short s_tz[GP * KNB];
  __shared__ __align__(4) unsigned short s_im[GP * KNB];
  __shared__ float s_cacc[GP][COUT];                           // 1024 B
  __shared__ float s_den[GP];                                  // 32 B

  const int tid = threadIdx.x;
  const int wv = tid >> 6;
  const int lane = tid & 63;
  const int c = lane & 15;          // phase-2 frag row (chan) / tap-in-tile
  const int g = lane >> 4;          // phase-2 edge group

  ((float*)s_cacc)[tid] = 0.0f;     // blockDim == GP*COUT == 256 exactly

  // ---- phase 0: coalesced nidx + hoisted feats gather; latency overlaps
  // phase 1. Lane<->edge mapping: flat edge (h*32+e) lives in lane (h*32+e). ----
  const int my_nb = nidx[blockIdx.x * (GP * KNB) + tid];
  float fpre[2][8];
#pragma unroll
  for (int h = 0; h < 2; ++h) {
#pragma unroll
    for (int j = 0; j < 8; ++j) {
      const int nb = __shfl(my_nb, h * 32 + g * 8 + j);
      fpre[h][j] = feats[nb * CIN + c];
    }
  }

  // ---- phase 1: geometry; all 64 lanes active (2 points per wave) ----
  {
    const int h = lane >> 5;          // which of the wave's 2 points
    const int e = lane & 31;          // edge
    const int p = wv * 2 + h;         // point-in-block
    const int pg = blockIdx.x * GP + p;
    const int eg = pg * KNB + e;      // == blockIdx*256 + tid
    const int nb = my_nb;
    const float d = ndist[eg];
    float q = 1.0f - d * d;
    float w6 = q * q * q;
    w6 = fminf(fmaxf(w6, 0.0f), 1.0f);
    const float imp = scale_compat[eg] * w6;

    const float inv = 1.0f / (0.5f * out_extents[pg]);
    const float rx = (inp_points[nb * 3 + 0] - out_points[pg * 3 + 0]) * inv;
    const float ry = (inp_points[nb * 3 + 1] - out_points[pg * 3 + 1]) * inv;
    const float rz = (inp_points[nb * 3 + 2] - out_points[pg * 3 + 2]) * inv;
    const float r = sqrtf(rx * rx + ry * ry + rz * rz);
    const float linf = fmaxf(fabsf(rx), fmaxf(fabsf(ry), fabsf(rz)));
    const float sf = r / fmaxf(linf, 1e-12f);
    const float tx = fminf(fmaxf((rx * sf * 0.5f + 0.5f) * 3.0f, 0.0f), 3.0f);
    const float ty = fminf(fmaxf((ry * sf * 0.5f + 0.5f) * 3.0f, 0.0f), 3.0f);
    const float tz = fminf(fmaxf((rz * sf * 0.5f + 0.5f) * 3.0f, 0.0f), 3.0f);

    // write index p*KNB+e == tid; 2B stride -> 2 lanes/bank (free)
    s_tx[tid] = f2hbits(tx);
    s_ty[tid] = f2hbits(ty);
    s_tz[tid] = f2hbits(tz);
    s_im[tid] = f2hbits(imp);

    float dsum = imp;                 // reduce within each 32-lane half
#pragma unroll
    for (int m = 1; m < 32; m <<= 1) dsum += __shfl_xor(dsum, m);
    if (e == 0) s_den[p] = dsum;
  }
  // NO barrier: phase 2 reads only this wave's own edge rows (same-wave LDS
  // ops execute in order).

  // ---- phase 2: per-point GEMM1 (transposed), packed-f16 2-wide hat math
  // via native h2v vector ops (v_pk_add/mul) + asm v_pk_max.
  // D1T(16c x 64t) = Fe^T * W^T; lane holds 4 consecutive CHANNELS of one
  // tap -> h2v results ARE the frag words. ----
  {
    const _Float16 kys = (_Float16)(short)(c >> 2);
    const _Float16 kzs = (_Float16)(short)(c & 3);
    const h2v z2 = {(_Float16)0, (_Float16)0};
    const h2v one2 = {(_Float16)1, (_Float16)1};
    const h2v two2 = {(_Float16)2, (_Float16)2};
    const h2v ky2 = {kys, kys};
    const h2v kz2 = {kzs, kzs};
#pragma unroll
    for (int h = 0; h < 2; ++h) {
      const int p = wv * 2 + h;
      union { unsigned int u[4]; h2v h[4]; half8 v; } wfr0, wfr1, wfr2, wfr3, fef;
#pragma unroll
      for (int jp = 0; jp < 4; ++jp) {       // edge pair: e = g*8 + 2jp, +1
        const int eb = p * KNB + g * 8 + jp * 2;
        const h2v tx2 = *(const h2v*)&s_tx[eb];
        const h2v ty2 = *(const h2v*)&s_ty[eb];
        const h2v tz2 = *(const h2v*)&s_tz[eb];
        const h2v im2 = *(const h2v*)&s_im[eb];
        h2v t = ty2 - ky2;
        h2v at = pmax(t, z2 - t);                    // |ty - ky|
        const h2v hy = pmax(z2, one2 - at);
        t = tz2 - kz2;
        at = pmax(t, z2 - t);
        const h2v hz = pmax(z2, one2 - at);
        const h2v m2 = hy * hz * im2;
        const h2v w0 = pmax(z2, one2 - tx2) * m2;    // tx >= 0
        t = tx2 - one2;
        at = pmax(t, z2 - t);
        const h2v w1 = pmax(z2, one2 - at) * m2;
        t = tx2 - two2;
        at = pmax(t, z2 - t);
        const h2v w2 = pmax(z2, one2 - at) * m2;
        const h2v w3 = pmax(z2, t) * m2;             // max(0, tx-2), tx <= 3
        wfr0.h[jp] = w0;
        wfr1.h[jp] = w1;
        wfr2.h[jp] = w2;
        wfr3.h[jp] = w3;
        fef.u[jp] = pkh(fpre[h][jp * 2], fpre[h][jp * 2 + 1]);
      }
      const f32x4 z = {0.f, 0.f, 0.f, 0.f};
      f32x4 d0 = __builtin_amdgcn_mfma_f32_16x16x32_f16(fef.v, wfr0.v, z, 0, 0, 0);
      f32x4 d1 = __builtin_amdgcn_mfma_f32_16x16x32_f16(fef.v, wfr1.v, z, 0, 0, 0);
      f32x4 d2 = __builtin_amdgcn_mfma_f32_16x16x32_f16(fef.v, wfr2.v, z, 0, 0, 0);
      f32x4 d3 = __builtin_amdgcn_mfma_f32_16x16x32_f16(fef.v, wfr3.v, z, 0, 0, 0);
      // lane holds chans {4g..4g+3} of tap (tile*16 + c); byte = t*32 + chan*2
      char* bp = s_bl + (unsigned)(p * ROW2B + c * 32 + g * 8);
      *(uint2*)(bp + 0 * 512) = make_uint2(pkh(d0[0], d0[1]), pkh(d0[2], d0[3]));
      *(uint2*)(bp + 1 * 512) = make_uint2(pkh(d1[0], d1[1]), pkh(d1[2], d1[3]));
      *(uint2*)(bp + 2 * 512) = make_uint2(pkh(d2[0], d2[1]), pkh(d2[2], d2[3]));
      *(uint2*)(bp + 3 * 512) = make_uint2(pkh(d3[0], d3[1]), pkh(d3[2], d3[3]));
    }
  }

  __syncthreads();

  // ---- phase 3: GEMM2. M-frame 16 (8 valid points), N = 32, K = 1024 over
  // 4 waves (8 ksteps of 32 each); A-frag is a raw b128 f16 read. ----
  f32x4 acc0 = {0.f, 0.f, 0.f, 0.f}, acc1 = {0.f, 0.f, 0.f, 0.f};
  const int pl = lane & 15;          // A row (mod GP) / B col selector
  const int arow = pl & (GP - 1);    // only GP point-rows exist
  const int g4 = lane >> 4;
#pragma unroll
  for (int ss = 0; ss < 8; ++ss) {
    const int s = wv * 8 + ss;
    const half8 a = *(const half8*)(s_bl + arow * ROW2B + s * 64 + g4 * 16);
    const half8 b0 = *(const half8*)(wf + ((unsigned)((s * 4 + g4) * 32) + pl) * 8);
    const half8 b1 = *(const half8*)(wf + ((unsigned)((s * 4 + g4) * 32) + 16 + pl) * 8);
    acc0 = __builtin_amdgcn_mfma_f32_16x16x32_f16(a, b0, acc0, 0, 0, 0);
    acc1 = __builtin_amdgcn_mfma_f32_16x16x32_f16(a, b1, acc1, 0, 0, 0);
  }
#pragma unroll
  for (int j = 0; j < 4; ++j) {
    const int row = g4 * 4 + j;      // D row = point; rows >= GP are duplicates
    if (row < GP) {
      atomicAdd(&s_cacc[row][pl], acc0[j]);
      atomicAdd(&s_cacc[row][pl + 16], acc1[j]);
    }
  }

  __syncthreads();

  // ---- epilogue: normalize, bias, relu; 256 threads == 256 outputs ----
  {
    const int p = tid >> 5;
    const int dch = tid & 31;
    const float den = s_den[p];
    float v = ((float*)s_cacc)[tid] / (den > 0.0f ? den : 1.0f) + bias[dch];
    out[blockIdx.x * (GP * COUT) + tid] = fmaxf(v, 0.0f);
  }
}

extern "C" void kernel_launch(void* const* d_in, const int* in_sizes, int n_in,
                              void* d_out, int out_size, void* d_ws, size_t ws_size,
                              hipStream_t stream) {
  const float* feats        = (const float*)d_in[0];
  const float* inp_points   = (const float*)d_in[1];
  const float* out_points   = (const float*)d_in[2];
  const float* out_extents  = (const float*)d_in[3];
  const float* scale_compat = (const float*)d_in[4];
  const int*   nidx         = (const int*)d_in[5];
  const float* ndist        = (const float*)d_in[7];
  const float* kern         = (const float*)d_in[8];
  const float* bias         = (const float*)d_in[9];
  unsigned short* wf = (unsigned short*)d_ws;  // 64 KiB frag-ordered f16 kernel

  prep_w_kernel<<<(NTAP * CIN * COUT + 255) / 256, 256, 0, stream>>>(kern, wf);
  cconv_kernel<<<NOUT / GP, 256, 0, stream>>>(feats, inp_points, out_points,
                                              out_extents, scale_compat, nidx,
                                              ndist, wf, bias, (float*)d_out);
}